// Round 4
// baseline (435.087 us; speedup 1.0000x reference)
//
#include <hip/hip_runtime.h>

#define DD     256   // feature dim
#define CC     100   // num classes
#define SLICES 4     // column slices of the feature dim
#define SCOLS  64    // columns per slice
#define PAD    65    // padded LDS row stride (floats) -> breaks bank aliasing
#define RGRPS  256   // row groups (blocks per slice)
#define BT     256   // threads per block

// Workspace layout (bytes):
//   [0, 102400)        : g_sums   (CC*DD f32)
//   [102400, 102800)   : g_counts (CC int)
//   [102800, 102808)   : g_sumsq  (1 double)
//   [103424, +4N)      : cls      (N int)
//   [aligned, ...)     : partials (SLICES*RGRPS * CC*SCOLS f32)
#define WS_SUMS_OFF   0
#define WS_COUNTS_OFF (CC * DD * 4)
#define WS_SUMSQ_OFF  (WS_COUNTS_OFF + CC * 4)
#define WS_HDR        (WS_SUMSQ_OFF + 8)
#define WS_CLS_OFF    103424

// ---------------- kernel A: per-row argmax of labels ------------------------
__global__ __launch_bounds__(BT, 4) void k_argmax(
        const float* __restrict__ labels,
        int*   __restrict__ cls,
        int*   __restrict__ g_counts,
        int N)
{
    __shared__ int s_cnt[CC];
    const int tid = threadIdx.x;
    if (tid < CC) s_cnt[tid] = 0;
    __syncthreads();

    const long long row = (long long)blockIdx.x * BT + tid;
    if (row < (long long)N) {
        const float4* l4 = (const float4*)(labels + row * (long long)CC);
        float4 q[CC / 4];
        #pragma unroll
        for (int j = 0; j < CC / 4; ++j) q[j] = l4[j];   // 25 independent loads
        float best = q[0].x;
        int   bi   = 0;
        #pragma unroll
        for (int j = 0; j < CC / 4; ++j) {               // first-max (strict >)
            if (q[j].x > best) { best = q[j].x; bi = 4 * j; }
            if (q[j].y > best) { best = q[j].y; bi = 4 * j + 1; }
            if (q[j].z > best) { best = q[j].z; bi = 4 * j + 2; }
            if (q[j].w > best) { best = q[j].w; bi = 4 * j + 3; }
        }
        cls[row] = bi;
        atomicAdd(&s_cnt[bi], 1);                        // native int LDS atomic
    }
    __syncthreads();
    if (tid < CC) {
        const int c = s_cnt[tid];
        if (c) atomicAdd(&g_counts[tid], c);
    }
}

// ---------------- kernel B: D-sliced class-sum accumulate -------------------
__global__ __launch_bounds__(BT, 4) void k_accum(
        const float* __restrict__ feats,
        const int*   __restrict__ cls,
        float* __restrict__ g_partials,
        float* __restrict__ g_sums,
        double* __restrict__ g_sumsq,
        int use_partials,
        int N, int rows_per_blk)
{
    __shared__ float  s_sums[CC * PAD];   // ~26 KB -> 4+ blocks/CU
    __shared__ double s_red[BT / 64];

    const int tid = threadIdx.x;
    for (int i = tid; i < CC * PAD; i += BT) s_sums[i] = 0.f;
    __syncthreads();

    const int lane  = tid & 63;
    const int wid   = tid >> 6;
    const int slice = blockIdx.x / RGRPS;
    const int rgrp  = blockIdx.x % RGRPS;
    const int d0    = slice * SCOLS;
    const int rsub  = lane >> 4;          // which of 4 rows this lane handles
    const int cq    = lane & 15;          // which float4 within the 64-col slice

    // this wave's row for iteration `it` is row0 + it (block covers 16 rows/iter)
    const long long row0 = (long long)rgrp * rows_per_blk + wid * 4 + rsub;

    float sumsq = 0.f;

    // ---- 2-deep software pipeline ----
    float4 f_a = {0,0,0,0}, f_b = {0,0,0,0};
    int    c_a = -1, c_b = -1;
    {
        const long long ra = row0, rb = row0 + 16;
        if (ra < (long long)N) {
            f_a = *(const float4*)(feats + ra * DD + d0 + cq * 4);
            c_a = cls[ra];
        }
        if (rb < (long long)N) {
            f_b = *(const float4*)(feats + rb * DD + d0 + cq * 4);
            c_b = cls[rb];
        }
    }

    for (int it = 0; it < rows_per_blk; it += 16) {
        // prefetch it+32
        float4 f_n = {0,0,0,0};
        int    c_n = -1;
        const long long rn = row0 + it + 32;
        if (it + 32 < rows_per_blk && rn < (long long)N) {
            f_n = *(const float4*)(feats + rn * DD + d0 + cq * 4);
            c_n = cls[rn];
        }
        // process current
        if (c_a >= 0) {
            sumsq += f_a.x * f_a.x + f_a.y * f_a.y + f_a.z * f_a.z + f_a.w * f_a.w;
            float* dst = &s_sums[c_a * PAD + cq * 4];
            unsafeAtomicAdd(dst + 0, f_a.x);   // ds_add_f32, fire-and-forget
            unsafeAtomicAdd(dst + 1, f_a.y);
            unsafeAtomicAdd(dst + 2, f_a.z);
            unsafeAtomicAdd(dst + 3, f_a.w);
        }
        f_a = f_b; c_a = c_b;
        f_b = f_n; c_b = c_n;
    }

    // ---- sumsq: wave reduce -> block reduce -> one f64 atomic per block ----
    double ds = (double)sumsq;
    #pragma unroll
    for (int off = 1; off < 64; off <<= 1) ds += __shfl_xor(ds, off);
    if (lane == 0) s_red[wid] = ds;
    __syncthreads();   // also drains all ds_add_f32
    if (tid == 0) {
        double t = 0.0;
        #pragma unroll
        for (int i = 0; i < BT / 64; ++i) t += s_red[i];
        atomicAdd(g_sumsq, t);
    }

    // ---- flush this block's [CC][SCOLS] tile ----
    if (use_partials) {
        float* dst = g_partials + (size_t)blockIdx.x * (CC * SCOLS);
        for (int i = tid; i < CC * SCOLS; i += BT)
            dst[i] = s_sums[(i >> 6) * PAD + (i & 63)];
    } else {
        for (int i = tid; i < CC * SCOLS; i += BT) {
            const float s = s_sums[(i >> 6) * PAD + (i & 63)];
            if (s != 0.f)
                unsafeAtomicAdd(&g_sums[(i >> 6) * DD + d0 + (i & 63)], s);
        }
    }
}

// ---------------- kernel R: reduce partials -> g_sums -----------------------
__global__ __launch_bounds__(DD) void k_reduce(
        const float* __restrict__ g_partials,
        float* __restrict__ g_sums)
{
    const int c = blockIdx.x;            // class
    const int d = threadIdx.x;           // global dim 0..255
    const int s = d >> 6;                // slice
    const int col = d & 63;
    const float* p = g_partials + (size_t)(s * RGRPS) * (CC * SCOLS) + c * SCOLS + col;
    double acc = 0.0;
    #pragma unroll 4
    for (int r = 0; r < RGRPS; ++r)
        acc += (double)p[(size_t)r * (CC * SCOLS)];   // coalesced across threads
    g_sums[c * DD + d] = (float)acc;
}

// ---------------- finalize ---------------------------------------------------
__global__ __launch_bounds__(DD) void affinity_finalize(
        const float* __restrict__ g_sums,
        const int*   __restrict__ g_counts,
        const double* __restrict__ g_sumsq,
        float* __restrict__ out)
{
    const int d = threadIdx.x;

    double colsum = 0.0, s2 = 0.0, dot = 0.0, cc = 0.0;
    for (int c = 0; c < CC; ++c) {
        const int    cnt = g_counts[c];
        const float  s   = g_sums[c * DD + d];
        const double center = (cnt > 0 ? (double)s / (double)cnt : 0.0) + 1e-6;
        colsum += center;
        s2     += center * center;
        dot    += center * (double)s;
        cc     += (double)cnt * center * center;
    }
    double interp = s2 - colsum * colsum / (double)CC;

    __shared__ double red0[DD], red1[DD], red2[DD];
    red0[d] = dot; red1[d] = cc; red2[d] = interp;
    __syncthreads();
    for (int off = DD / 2; off > 0; off >>= 1) {
        if (d < off) {
            red0[d] += red0[d + off];
            red1[d] += red1[d + off];
            red2[d] += red2[d + off];
        }
        __syncthreads();
    }
    if (d == 0) {
        const double intra = *g_sumsq - 2.0 * red0[0] + red1[0];
        const double inter = red2[0] / (double)CC;
        out[0] = (float)(intra / (inter + 1e-6));
    }
}

extern "C" void kernel_launch(void* const* d_in, const int* in_sizes, int n_in,
                              void* d_out, int out_size, void* d_ws, size_t ws_size,
                              hipStream_t stream)
{
    const float* feats  = (const float*)d_in[0];
    const float* labels = (const float*)d_in[1];
    const int N = in_sizes[0] / DD;

    float*  g_sums   = (float*)((char*)d_ws + WS_SUMS_OFF);
    int*    g_counts = (int*)((char*)d_ws + WS_COUNTS_OFF);
    double* g_sumsq  = (double*)((char*)d_ws + WS_SUMSQ_OFF);
    int*    cls      = (int*)((char*)d_ws + WS_CLS_OFF);

    const size_t part_off = ((size_t)WS_CLS_OFF + (size_t)N * 4 + 255) & ~(size_t)255;
    float* g_partials = (float*)((char*)d_ws + part_off);

    // rows per accumulate block: multiple of 32, covering N over RGRPS groups
    int rpb = (N + RGRPS - 1) / RGRPS;
    rpb = (rpb + 31) & ~31;

    const size_t need = part_off + (size_t)SLICES * RGRPS * (CC * SCOLS) * 4;
    const int use_partials = (ws_size >= need) ? 1 : 0;

    hipMemsetAsync(d_ws, 0, WS_HDR, stream);   // zero g_sums/g_counts/g_sumsq

    const int nblocksA = (N + BT - 1) / BT;
    k_argmax<<<nblocksA, BT, 0, stream>>>(labels, cls, g_counts, N);

    k_accum<<<SLICES * RGRPS, BT, 0, stream>>>(feats, cls, g_partials, g_sums,
                                               g_sumsq, use_partials, N, rpb);
    if (use_partials)
        k_reduce<<<CC, DD, 0, stream>>>(g_partials, g_sums);

    affinity_finalize<<<1, DD, 0, stream>>>(g_sums, g_counts, g_sumsq,
                                            (float*)d_out);
}